// Round 1
// baseline (9884.104 us; speedup 1.0000x reference)
//
#include <hip/hip_runtime.h>

#define HW_ (512 * 512)
#define B_ 8
#define H_ 512
#define W_ 512
#define K_ 32

// -------- DPP min helper (quad_perm / row mirrors), 32-lane reduce --------
template <int CTRL>
__device__ __forceinline__ float fmin_dpp(float x) {
  int r = __builtin_amdgcn_update_dpp(0, __float_as_int(x), CTRL, 0xF, 0xF, true);
  return fminf(x, __int_as_float(r));
}

// ---------------- kernel 1: ordered compaction + embedding gather ----------------
__global__ void k_compact(const float* __restrict__ seg, const float* __restrict__ emb,
                          unsigned char* __restrict__ lanes, int* __restrict__ idxC,
                          float* __restrict__ embC, int* __restrict__ nvalid, int cap) {
  const int b = blockIdx.x;
  const int t = threadIdx.x;
  const float* __restrict__ s = seg + (size_t)b * HW_;
  const int base = t * 256;  // 1024 threads x 256 contiguous pixels
  const float4* __restrict__ s4 = (const float4*)(s + base);

  // pass 1: count valid in my chunk
  int cnt = 0;
  for (int j = 0; j < 64; ++j) {
    float4 v = s4[j];
    cnt += (v.x >= 0.9f) + (v.y >= 0.9f) + (v.z >= 0.9f) + (v.w >= 0.9f);
  }
  __shared__ int pre[1024];
  pre[t] = cnt;
  __syncthreads();
  for (int off = 1; off < 1024; off <<= 1) {
    int mine = pre[t];
    int add = (t >= off) ? pre[t - off] : 0;
    __syncthreads();
    pre[t] = mine + add;
    __syncthreads();
  }
  int w = pre[t] - cnt;  // exclusive prefix (pixel-ordered)
  if (t == 1023) nvalid[b] = min(pre[t], cap);

  const float* __restrict__ eb = emb + (size_t)b * 8 * HW_;
  unsigned char* __restrict__ lb = lanes + (size_t)b * HW_ + base;
  int* __restrict__ ib = idxC + (size_t)b * cap;
  float* __restrict__ ebc = embC + (size_t)b * cap * 8;

  for (int j = 0; j < 64; ++j) {
    float4 v = s4[j];
    float sv[4] = {v.x, v.y, v.z, v.w};
#pragma unroll
    for (int q = 0; q < 4; ++q) {
      const int p = base + j * 4 + q;
      lb[j * 4 + q] = 0;  // default lane (cid = -1); valid pixels overwritten by k_cluster
      if (sv[q] >= 0.9f && w < cap) {
        ib[w] = p;
        float* dst = ebc + (size_t)w * 8;
#pragma unroll
        for (int d = 0; d < 8; ++d) dst[d] = eb[(size_t)d * HW_ + p];
        ++w;
      }
    }
  }
}

// ---------------- kernel 2: sequential clustering, 1 wave per batch ----------------
__global__ __launch_bounds__(64, 1) void k_cluster(const int* __restrict__ idxC,
                                                   const float* __restrict__ embC,
                                                   const int* __restrict__ nvalid,
                                                   unsigned char* __restrict__ lanes, int cap) {
  const int b = blockIdx.x;
  const int lane = threadIdx.x;
  const int cl = lane & 31;  // my center id (upper half replicates lower)
  const int n = nvalid[b];
  const float4* __restrict__ eb = (const float4*)(embC + (size_t)b * cap * 8);
  const int* __restrict__ ib = idxC + (size_t)b * cap;
  unsigned char* __restrict__ lb = lanes + (size_t)b * HW_;

  float c0 = 0, c1 = 0, c2 = 0, c3 = 0, c4 = 0, c5 = 0, c6 = 0, c7 = 0, cnt = 0;

  // 4-deep prefetch, static register slots (no runtime indexing -> no scratch)
  float4 a0, a1, a2, a3, v0, v1, v2, v3;
  int p0 = 0, p1 = 0, p2 = 0, p3 = 0;
  if (0 < n) { a0 = eb[0]; v0 = eb[1]; p0 = ib[0]; }
  if (1 < n) { a1 = eb[2]; v1 = eb[3]; p1 = ib[1]; }
  if (2 < n) { a2 = eb[4]; v2 = eb[5]; p2 = ib[2]; }
  if (3 < n) { a3 = eb[6]; v3 = eb[7]; p3 = ib[3]; }

  for (int ii = 0; ii < n; ii += 4) {
#pragma unroll
    for (int j = 0; j < 4; ++j) {
      const int i = ii + j;
      if (i >= n) break;  // wave-uniform
      float4 A, Bv;
      int p;
      if (j == 0) { A = a0; Bv = v0; p = p0; }
      else if (j == 1) { A = a1; Bv = v1; p = p1; }
      else if (j == 2) { A = a2; Bv = v2; p = p2; }
      else { A = a3; Bv = v3; p = p3; }
      const int nx = i + 4;
      if (nx < n) {
        if (j == 0) { a0 = eb[2 * nx]; v0 = eb[2 * nx + 1]; p0 = ib[nx]; }
        else if (j == 1) { a1 = eb[2 * nx]; v1 = eb[2 * nx + 1]; p1 = ib[nx]; }
        else if (j == 2) { a2 = eb[2 * nx]; v2 = eb[2 * nx + 1]; p2 = ib[nx]; }
        else { a3 = eb[2 * nx]; v3 = eb[2 * nx + 1]; p3 = ib[nx]; }
      }

      // squared distance to my center (tree sum, matches numpy's n=8 pairwise shape)
      float t0 = c0 - A.x, t1 = c1 - A.y, t2 = c2 - A.z, t3 = c3 - A.w;
      float t4 = c4 - Bv.x, t5 = c5 - Bv.y, t6 = c6 - Bv.z, t7 = c7 - Bv.w;
      float dsq = ((t0 * t0 + t1 * t1) + (t2 * t2 + t3 * t3)) +
                  ((t4 * t4 + t5 * t5) + (t6 * t6 + t7 * t7));
      float d = (cnt > 0.0f) ? dsq : __builtin_inff();

      // min over 32 centers: 4 DPP steps (pairs, quads, 8s, 16s) + xor16 swizzle
      float m = d;
      m = fmin_dpp<0xB1>(m);   // quad_perm(1,0,3,2)  : xor 1
      m = fmin_dpp<0x4E>(m);   // quad_perm(2,3,0,1)  : xor 2
      m = fmin_dpp<0x141>(m);  // row_half_mirror     : cross quads in 8-group
      m = fmin_dpp<0x140>(m);  // row_mirror          : cross 8s in 16-group
      {
        int r = __builtin_amdgcn_ds_swizzle(__float_as_int(m), 0x401F);  // xor 16
        m = fminf(m, __int_as_float(r));
      }

      unsigned long long bal = __ballot(d == m);
      int cidmin = (__ffsll(bal) - 1) & 31;  // lowest lane == lowest center index (argmin tie-break)
      bool join = (m < 9.0f);                // sqrt(d) < 3  <=>  d < 9 (exact, monotone)
      unsigned long long act = __ballot(cnt > 0.0f);
      int nact = __popcll(act & 0xffffffffULL);
      int cid = join ? cidmin : min(nact, 31);

      if (cl == cid) {
        if (join) {
          float inv = 1.0f / (cnt + 1.0f);
          c0 = (c0 * cnt + A.x) * inv;  c1 = (c1 * cnt + A.y) * inv;
          c2 = (c2 * cnt + A.z) * inv;  c3 = (c3 * cnt + A.w) * inv;
          c4 = (c4 * cnt + Bv.x) * inv; c5 = (c5 * cnt + Bv.y) * inv;
          c6 = (c6 * cnt + Bv.z) * inv; c7 = (c7 * cnt + Bv.w) * inv;
        } else {
          c0 = A.x; c1 = A.y; c2 = A.z; c3 = A.w;
          c4 = Bv.x; c5 = Bv.y; c6 = Bv.z; c7 = Bv.w;
        }
        cnt += 1.0f;
      }
      if (lane == 0) lb[p] = (unsigned char)(cid + 1);
    }
  }
}

// ---------------- kernel 3: per-(b,h) segment sums over 33 lane bins ----------------
__global__ void k_rowsum(const unsigned char* __restrict__ lanes,
                         const float* __restrict__ offp, const float* __restrict__ zp,
                         float* __restrict__ cnt, float* __restrict__ sx,
                         float* __restrict__ sz) {
  const int bh = blockIdx.x;
  const int b = bh >> 9, h = bh & 511;
  __shared__ float sc[33], sxx[33], szz[33];
  const int t = threadIdx.x;
  if (t < 33) { sc[t] = 0.f; sxx[t] = 0.f; szz[t] = 0.f; }
  __syncthreads();
  const size_t base = (size_t)bh * W_;
  for (int x = t; x < W_; x += 256) {
    int ln = lanes[base + x];
    float o = offp[base + x];
    float sig = 1.0f / (1.0f + expf(-o));
    float xa = (float)x + sig;
    float zv = zp[base + x];
    atomicAdd(&sc[ln], 1.0f);
    atomicAdd(&sxx[ln], xa);
    atomicAdd(&szz[ln], zv);
  }
  __syncthreads();
  if (t >= 1 && t < 33) {
    size_t o = ((size_t)b * K_ + (t - 1)) * H_ + h;
    cnt[o] = sc[t]; sx[o] = sxx[t]; sz[o] = szz[t];
  }
}

// ---------------- kernel 4: validity + point assembly ----------------
__global__ void k_final(const float* __restrict__ cnt, const float* __restrict__ sx,
                        const float* __restrict__ sz, float* __restrict__ out) {
  const int bk = blockIdx.x;
  const int b = bk >> 5, k = bk & 31;
  const int h = threadIdx.x;
  const size_t o = (size_t)bk * H_ + h;
  float c = cnt[o];
  float sc_ = c, sn = (c > 0.f) ? 1.f : 0.f;
#pragma unroll
  for (int off = 32; off >= 1; off >>= 1) {
    sc_ += __shfl_down(sc_, off);
    sn += __shfl_down(sn, off);
  }
  __shared__ float rs[8], rn[8], tot[2];
  const int wid = h >> 6, lid = h & 63;
  if (lid == 0) { rs[wid] = sc_; rn[wid] = sn; }
  __syncthreads();
  if (h == 0) {
    float a = 0, bb = 0;
#pragma unroll
    for (int q = 0; q < 8; ++q) { a += rs[q]; bb += rn[q]; }
    tot[0] = a; tot[1] = bb;
  }
  __syncthreads();
  float size = tot[0], nrows = tot[1];
  bool valid = (c > 0.f) && (size >= 50.f) && (nrows >= 2.f);
  float mx = sx[o] / fmaxf(c, 1.f);
  float mz = sz[o] / fmaxf(c, 1.f);
  float xw = (512.0f - ((float)h + 0.5f)) * 0.2f;  // (MAX_X/MPP0 - (h+0.5)) * MPP0
  float yw = -(mx - 256.0f) * 0.2f;                // -(mean_x - W/2) * MPP1
  out[((size_t)(b * 3 + 0) * K_ + k) * H_ + h] = valid ? xw : 0.f;
  out[((size_t)(b * 3 + 1) * K_ + k) * H_ + h] = valid ? yw : 0.f;
  out[((size_t)(b * 3 + 2) * K_ + k) * H_ + h] = valid ? mz : 0.f;
  out[(size_t)B_ * 3 * K_ * H_ + (size_t)bk * H_ + h] = valid ? 1.f : 0.f;
}

extern "C" void kernel_launch(void* const* d_in, const int* in_sizes, int n_in,
                              void* d_out, int out_size, void* d_ws, size_t ws_size,
                              hipStream_t stream) {
  const float* seg  = (const float*)d_in[0];
  const float* emb  = (const float*)d_in[1];
  const float* offp = (const float*)d_in[2];
  const float* zp   = (const float*)d_in[3];
  float* out = (float*)d_out;
  char* ws = (char*)d_ws;

  // ws layout
  const size_t lanesOff = 0;                                   // B*HW bytes
  const size_t cntOff   = (size_t)B_ * HW_;                    // +2 MiB
  const size_t sxOff    = cntOff + (size_t)B_ * K_ * H_ * 4;
  const size_t szOff    = sxOff  + (size_t)B_ * K_ * H_ * 4;
  const size_t nvOff    = szOff  + (size_t)B_ * K_ * H_ * 4;
  const size_t idxOff   = nvOff + 256;
  size_t avail = (ws_size > idxOff) ? (ws_size - idxOff) : 0;
  long long capLL = (long long)(avail / ((size_t)B_ * 36));    // 4B idx + 32B emb per entry
  if (capLL > (long long)HW_) capLL = HW_;
  if (capLL < 1) capLL = 1;
  const int cap = (int)capLL;
  const size_t embOff = idxOff + (size_t)B_ * cap * 4;

  unsigned char* lanes = (unsigned char*)(ws + lanesOff);
  float* cnt = (float*)(ws + cntOff);
  float* sx  = (float*)(ws + sxOff);
  float* sz  = (float*)(ws + szOff);
  int* nvalid = (int*)(ws + nvOff);
  int* idxC   = (int*)(ws + idxOff);
  float* embC = (float*)(ws + embOff);

  k_compact<<<B_, 1024, 0, stream>>>(seg, emb, lanes, idxC, embC, nvalid, cap);
  k_cluster<<<B_, 64, 0, stream>>>(idxC, embC, nvalid, lanes, cap);
  k_rowsum<<<B_ * H_, 256, 0, stream>>>(lanes, offp, zp, cnt, sx, sz);
  k_final<<<B_ * K_, H_, 0, stream>>>(cnt, sx, sz, out);
}

// Round 2
// 7218.587 us; speedup vs baseline: 1.3693x; 1.3693x over previous
//
#include <hip/hip_runtime.h>

#define HW_ (512 * 512)
#define B_ 8
#define H_ 512
#define W_ 512
#define K_ 32
#define CH_ 16
#define CHPIX_ (HW_ / CH_)  // 16384 pixels per chunk

// -------- DPP min helper (quad_perm / row mirrors) --------
template <int CTRL>
__device__ __forceinline__ float fmin_dpp(float x) {
  int r = __builtin_amdgcn_update_dpp(0, __float_as_int(x), CTRL, 0xF, 0xF, true);
  return fminf(x, __int_as_float(r));
}

// ---------------- compact phase A: per-chunk valid count ----------------
__global__ void k_count(const float* __restrict__ seg, int* __restrict__ chunkCnt) {
  const int blk = blockIdx.x;  // b*CH_ + c
  const int t = threadIdx.x;
  const float4* __restrict__ s4 = (const float4*)(seg + (size_t)blk * CHPIX_) + (size_t)t * 16;
  int cnt = 0;
#pragma unroll
  for (int j = 0; j < 16; ++j) {
    float4 v = s4[j];
    cnt += (v.x >= 0.9f) + (v.y >= 0.9f) + (v.z >= 0.9f) + (v.w >= 0.9f);
  }
  __shared__ int red[256];
  red[t] = cnt;
  __syncthreads();
  for (int off = 128; off > 0; off >>= 1) {
    if (t < off) red[t] += red[t + off];
    __syncthreads();
  }
  if (t == 0) chunkCnt[blk] = red[0];
}

// ---------------- compact phase B: per-batch chunk base offsets ----------------
__global__ void k_scan(const int* __restrict__ chunkCnt, int* __restrict__ chunkBase,
                       int* __restrict__ nvalid, int cap) {
  const int t = threadIdx.x;  // b*CH_ + c
  if (t < B_ * CH_) {
    const int b = t / CH_, c = t % CH_;
    int base = 0;
    for (int q = 0; q < c; ++q) base += chunkCnt[b * CH_ + q];
    chunkBase[t] = base;
    if (c == CH_ - 1) nvalid[b] = min(base + chunkCnt[t], cap);
  }
}

// ---------------- compact phase C: ordered compaction + gather + lanes memset ----------------
__global__ void k_fill(const float* __restrict__ seg, const float* __restrict__ emb,
                       const int* __restrict__ chunkBase, unsigned char* __restrict__ lanes,
                       int* __restrict__ idxC, float* __restrict__ embC, int cap) {
  const int blk = blockIdx.x;  // b*CH_ + c
  const int b = blk / CH_;
  const int t = threadIdx.x;
  const size_t pixbase = (size_t)blk * CHPIX_ + (size_t)t * 64;  // global pixel index incl. batch
  const float4* __restrict__ s4 = (const float4*)(seg + pixbase);

  int cnt = 0;
#pragma unroll
  for (int j = 0; j < 16; ++j) {
    float4 v = s4[j];
    cnt += (v.x >= 0.9f) + (v.y >= 0.9f) + (v.z >= 0.9f) + (v.w >= 0.9f);
  }
  __shared__ int pre[256];
  pre[t] = cnt;
  __syncthreads();
  for (int off = 1; off < 256; off <<= 1) {
    int mine = pre[t];
    int add = (t >= off) ? pre[t - off] : 0;
    __syncthreads();
    pre[t] = mine + add;
    __syncthreads();
  }
  int w = chunkBase[blk] + pre[t] - cnt;  // pixel-ordered exclusive prefix

  // zero lanes for my 64 pixels (16B vector stores)
  uint4 z = {0u, 0u, 0u, 0u};
  uint4* lz = (uint4*)(lanes + pixbase);
  lz[0] = z; lz[1] = z; lz[2] = z; lz[3] = z;

  const float* __restrict__ eb = emb + (size_t)b * 8 * HW_;
  const int pixInB = (int)(pixbase - (size_t)b * HW_);
  for (int j = 0; j < 16; ++j) {
    float4 v = s4[j];
    float sv[4] = {v.x, v.y, v.z, v.w};
#pragma unroll
    for (int q = 0; q < 4; ++q) {
      if (sv[q] >= 0.9f && w < cap) {
        const int p = pixInB + j * 4 + q;
        idxC[(size_t)b * cap + w] = p;
        float* dst = embC + ((size_t)b * cap + w) * 8;
#pragma unroll
        for (int dd = 0; dd < 8; ++dd) dst[dd] = eb[(size_t)dd * HW_ + p];
        ++w;
      }
    }
  }
}

// ---------------- sequential clustering: 1 wave per batch, straight-line ----------------
#define CSTEP(SA, SB, P, PFI)                                                        \
  {                                                                                  \
    float t0 = c0 - SA.x, t1 = c1 - SA.y, t2 = c2 - SA.z, t3 = c3 - SA.w;            \
    float t4 = c4 - SB.x, t5 = c5 - SB.y, t6 = c6 - SB.z, t7 = c7 - SB.w;            \
    float dsq = ((t0 * t0 + t1 * t1) + (t2 * t2 + t3 * t3)) +                        \
                ((t4 * t4 + t5 * t5) + (t6 * t6 + t7 * t7));                         \
    float d = (cnt > 0.0f) ? dsq : __builtin_inff();                                 \
    float inv = __builtin_amdgcn_rcpf(cnt + 1.0f);                                   \
    float j0 = (c0 * cnt + SA.x) * inv, j1 = (c1 * cnt + SA.y) * inv;                \
    float j2 = (c2 * cnt + SA.z) * inv, j3 = (c3 * cnt + SA.w) * inv;                \
    float j4 = (c4 * cnt + SB.x) * inv, j5 = (c5 * cnt + SB.y) * inv;                \
    float j6 = (c6 * cnt + SB.z) * inv, j7 = (c7 * cnt + SB.w) * inv;                \
    unsigned long long actb = __ballot(cnt > 0.0f);                                  \
    float m = d;                                                                     \
    m = fmin_dpp<0xB1>(m);  /* xor1 within quads */                                  \
    m = fmin_dpp<0x4E>(m);  /* xor2 within quads */                                  \
    m = fmin_dpp<0x141>(m); /* row_half_mirror: other quad in 8 */                   \
    m = fmin_dpp<0x140>(m); /* row_mirror: other 8 in 16 */                          \
    unsigned mu0 = (unsigned)__builtin_amdgcn_readlane(__float_as_int(m), 0);        \
    unsigned mu1 = (unsigned)__builtin_amdgcn_readlane(__float_as_int(m), 16);       \
    float mv = __uint_as_float(mu0 < mu1 ? mu0 : mu1);                               \
    unsigned long long bal = __ballot(d == mv);                                      \
    int cidmin = __ffsll(bal) - 1;                                                   \
    int nact = __popcll(actb & 0xffffffffULL);                                       \
    bool join = (mv < 9.0f); /* sqrt(d) < 3 <=> d < 9 */                             \
    int cid = join ? cidmin : (nact < 31 ? nact : 31);                               \
    bool own = (cl == cid);                                                          \
    float u0 = join ? j0 : SA.x, u1 = join ? j1 : SA.y;                              \
    float u2 = join ? j2 : SA.z, u3 = join ? j3 : SA.w;                              \
    float u4 = join ? j4 : SB.x, u5 = join ? j5 : SB.y;                              \
    float u6 = join ? j6 : SB.z, u7 = join ? j7 : SB.w;                              \
    c0 = own ? u0 : c0; c1 = own ? u1 : c1;                                          \
    c2 = own ? u2 : c2; c3 = own ? u3 : c3;                                          \
    c4 = own ? u4 : c4; c5 = own ? u5 : c5;                                          \
    c6 = own ? u6 : c6; c7 = own ? u7 : c7;                                          \
    cnt = own ? cnt + 1.0f : cnt;                                                    \
    pack |= (unsigned long long)(unsigned)(cid + 1) << ((P) * 8);                    \
    {                                                                                \
      int pf_ = (PFI);                                                               \
      pf_ = pf_ < n ? pf_ : n - 1;                                                   \
      SA = eb[2 * pf_]; SB = eb[2 * pf_ + 1];                                        \
    }                                                                                \
  }

#define LOADSLOT(SA, SB, IDX)                  \
  {                                            \
    int q_ = (IDX); q_ = q_ < n ? q_ : n - 1;  \
    SA = eb[2 * q_]; SB = eb[2 * q_ + 1];      \
  }

__global__ __launch_bounds__(64, 1) void k_cluster(const float* __restrict__ embC,
                                                   const int* __restrict__ nvalid,
                                                   unsigned long long* __restrict__ cidPk,
                                                   int cap) {
  const int b = blockIdx.x;
  const int lane = threadIdx.x;
  const int cl = lane & 31;  // my center id (upper half replicates lower)
  const int n = nvalid[b];
  if (n <= 0) return;
  const float4* __restrict__ eb = (const float4*)(embC + (size_t)b * cap * 8);
  unsigned long long* __restrict__ pkb = cidPk + (size_t)b * (HW_ / 8);

  float c0 = 0, c1 = 0, c2 = 0, c3 = 0, c4 = 0, c5 = 0, c6 = 0, c7 = 0, cnt = 0;
  unsigned long long pack = 0ULL;

  float4 s0A, s0B, s1A, s1B, s2A, s2B, s3A, s3B;
  float4 s4A, s4B, s5A, s5B, s6A, s6B, s7A, s7B;
  LOADSLOT(s0A, s0B, 0) LOADSLOT(s1A, s1B, 1) LOADSLOT(s2A, s2B, 2) LOADSLOT(s3A, s3B, 3)
  LOADSLOT(s4A, s4B, 4) LOADSLOT(s5A, s5B, 5) LOADSLOT(s6A, s6B, 6) LOADSLOT(s7A, s7B, 7)

  int i = 0;
  for (; i + 8 <= n; i += 8) {
    CSTEP(s0A, s0B, 0, i + 8)
    CSTEP(s1A, s1B, 1, i + 9)
    CSTEP(s2A, s2B, 2, i + 10)
    CSTEP(s3A, s3B, 3, i + 11)
    CSTEP(s4A, s4B, 4, i + 12)
    CSTEP(s5A, s5B, 5, i + 13)
    CSTEP(s6A, s6B, 6, i + 14)
    CSTEP(s7A, s7B, 7, i + 15)
    if (lane == 0) pkb[i >> 3] = pack;
    pack = 0ULL;
  }
  const int r = n - i;
  if (r > 0) {
    CSTEP(s0A, s0B, 0, n - 1)
    if (r > 1) CSTEP(s1A, s1B, 1, n - 1)
    if (r > 2) CSTEP(s2A, s2B, 2, n - 1)
    if (r > 3) CSTEP(s3A, s3B, 3, n - 1)
    if (r > 4) CSTEP(s4A, s4B, 4, n - 1)
    if (r > 5) CSTEP(s5A, s5B, 5, n - 1)
    if (r > 6) CSTEP(s6A, s6B, 6, n - 1)
    if (lane == 0) pkb[i >> 3] = pack;
  }
}

// ---------------- scatter packed cids to the per-pixel lane map ----------------
__global__ void k_scatter(const unsigned long long* __restrict__ cidPk,
                          const int* __restrict__ idxC, const int* __restrict__ nvalid,
                          unsigned char* __restrict__ lanes, int cap) {
  const int b = blockIdx.y;
  const int n = nvalid[b];
  for (int j = blockIdx.x * blockDim.x + threadIdx.x; j < n; j += gridDim.x * blockDim.x) {
    unsigned long long pk = cidPk[(size_t)b * (HW_ / 8) + (j >> 3)];
    unsigned char v = (unsigned char)((pk >> ((j & 7) * 8)) & 0xff);
    lanes[(size_t)b * HW_ + idxC[(size_t)b * cap + j]] = v;
  }
}

// ---------------- per-(b,h) segment sums over 33 lane bins ----------------
__global__ void k_rowsum(const unsigned char* __restrict__ lanes,
                         const float* __restrict__ offp, const float* __restrict__ zp,
                         float* __restrict__ cnt, float* __restrict__ sx,
                         float* __restrict__ sz) {
  const int bh = blockIdx.x;
  const int b = bh >> 9, h = bh & 511;
  __shared__ float sc[33], sxx[33], szz[33];
  const int t = threadIdx.x;
  if (t < 33) { sc[t] = 0.f; sxx[t] = 0.f; szz[t] = 0.f; }
  __syncthreads();
  const size_t base = (size_t)bh * W_;
  for (int x = t; x < W_; x += 256) {
    int ln = lanes[base + x];
    float o = offp[base + x];
    float sig = 1.0f / (1.0f + expf(-o));
    float xa = (float)x + sig;
    float zv = zp[base + x];
    atomicAdd(&sc[ln], 1.0f);
    atomicAdd(&sxx[ln], xa);
    atomicAdd(&szz[ln], zv);
  }
  __syncthreads();
  if (t >= 1 && t < 33) {
    size_t o = ((size_t)b * K_ + (t - 1)) * H_ + h;
    cnt[o] = sc[t]; sx[o] = sxx[t]; sz[o] = szz[t];
  }
}

// ---------------- validity + point assembly ----------------
__global__ void k_final(const float* __restrict__ cnt, const float* __restrict__ sx,
                        const float* __restrict__ sz, float* __restrict__ out) {
  const int bk = blockIdx.x;
  const int b = bk >> 5, k = bk & 31;
  const int h = threadIdx.x;
  const size_t o = (size_t)bk * H_ + h;
  float c = cnt[o];
  float sc_ = c, sn = (c > 0.f) ? 1.f : 0.f;
#pragma unroll
  for (int off = 32; off >= 1; off >>= 1) {
    sc_ += __shfl_down(sc_, off);
    sn += __shfl_down(sn, off);
  }
  __shared__ float rs[8], rn[8], tot[2];
  const int wid = h >> 6, lid = h & 63;
  if (lid == 0) { rs[wid] = sc_; rn[wid] = sn; }
  __syncthreads();
  if (h == 0) {
    float a = 0, bb = 0;
#pragma unroll
    for (int q = 0; q < 8; ++q) { a += rs[q]; bb += rn[q]; }
    tot[0] = a; tot[1] = bb;
  }
  __syncthreads();
  float size = tot[0], nrows = tot[1];
  bool valid = (c > 0.f) && (size >= 50.f) && (nrows >= 2.f);
  float mx = sx[o] / fmaxf(c, 1.f);
  float mz = sz[o] / fmaxf(c, 1.f);
  float xw = (512.0f - ((float)h + 0.5f)) * 0.2f;
  float yw = -(mx - 256.0f) * 0.2f;
  out[((size_t)(b * 3 + 0) * K_ + k) * H_ + h] = valid ? xw : 0.f;
  out[((size_t)(b * 3 + 1) * K_ + k) * H_ + h] = valid ? yw : 0.f;
  out[((size_t)(b * 3 + 2) * K_ + k) * H_ + h] = valid ? mz : 0.f;
  out[(size_t)B_ * 3 * K_ * H_ + (size_t)bk * H_ + h] = valid ? 1.f : 0.f;
}

extern "C" void kernel_launch(void* const* d_in, const int* in_sizes, int n_in,
                              void* d_out, int out_size, void* d_ws, size_t ws_size,
                              hipStream_t stream) {
  const float* seg  = (const float*)d_in[0];
  const float* emb  = (const float*)d_in[1];
  const float* offp = (const float*)d_in[2];
  const float* zp   = (const float*)d_in[3];
  float* out = (float*)d_out;
  char* ws = (char*)d_ws;

  // ws layout (all offsets multiples of 256)
  const size_t lanesOff = 0;                                    // B*HW bytes (2 MiB)
  const size_t cntOff   = (size_t)B_ * HW_;
  const size_t sxOff    = cntOff + (size_t)B_ * K_ * H_ * 4;
  const size_t szOff    = sxOff  + (size_t)B_ * K_ * H_ * 4;
  const size_t nvOff    = szOff  + (size_t)B_ * K_ * H_ * 4;
  const size_t ccOff    = nvOff + 256;                          // chunkCnt (128 ints)
  const size_t cbOff    = ccOff + 1024;                         // chunkBase (128 ints)
  const size_t pkOff    = cbOff + 1024;                         // packed cids, B*HW/8*8 = 2 MiB
  const size_t idxOff   = pkOff + (size_t)B_ * (HW_ / 8) * 8;
  size_t avail = (ws_size > idxOff) ? (ws_size - idxOff) : 0;
  long long capLL = (long long)(avail / ((size_t)B_ * 36));     // 4B idx + 32B emb per entry
  if (capLL > (long long)HW_) capLL = HW_;
  if (capLL < 1) capLL = 1;
  const int cap = (int)capLL;
  const size_t embOff = idxOff + (size_t)B_ * cap * 4;

  unsigned char* lanes = (unsigned char*)(ws + lanesOff);
  float* cnt = (float*)(ws + cntOff);
  float* sx  = (float*)(ws + sxOff);
  float* sz  = (float*)(ws + szOff);
  int* nvalid = (int*)(ws + nvOff);
  int* chunkCnt  = (int*)(ws + ccOff);
  int* chunkBase = (int*)(ws + cbOff);
  unsigned long long* cidPk = (unsigned long long*)(ws + pkOff);
  int* idxC   = (int*)(ws + idxOff);
  float* embC = (float*)(ws + embOff);

  k_count<<<B_ * CH_, 256, 0, stream>>>(seg, chunkCnt);
  k_scan<<<1, 128, 0, stream>>>(chunkCnt, chunkBase, nvalid, cap);
  k_fill<<<B_ * CH_, 256, 0, stream>>>(seg, emb, chunkBase, lanes, idxC, embC, cap);
  k_cluster<<<B_, 64, 0, stream>>>(embC, nvalid, cidPk, cap);
  k_scatter<<<dim3(64, B_), 256, 0, stream>>>(cidPk, idxC, nvalid, lanes, cap);
  k_rowsum<<<B_ * H_, 256, 0, stream>>>(lanes, offp, zp, cnt, sx, sz);
  k_final<<<B_ * K_, H_, 0, stream>>>(cnt, sx, sz, out);
}